// Round 1
// baseline (468.352 us; speedup 1.0000x reference)
//
#include <hip/hip_runtime.h>
#include <stdint.h>
#include <stddef.h>

#define IN_F  4096
#define OUT_F 4096
#define BATCH 8192

typedef _Float16 f16;
typedef _Float16 f16x4 __attribute__((ext_vector_type(4)));
typedef _Float16 f16x8 __attribute__((ext_vector_type(8)));
typedef float    f32x4 __attribute__((ext_vector_type(4)));

// ---------------- helpers ----------------

__device__ __forceinline__ float softplus_f(float x) {
    // log(1+e^x) = max(x,0) + log1p(e^-|x|)
    return fmaxf(x, 0.0f) + log1pf(__expf(-fabsf(x)));
}

__device__ __forceinline__ void block_reduce_atomic(float v, float* dst) {
    #pragma unroll
    for (int off = 32; off > 0; off >>= 1) v += __shfl_down(v, off, 64);
    __shared__ float parts[16];
    const int lane = threadIdx.x & 63, wave = threadIdx.x >> 6;
    if (lane == 0) parts[wave] = v;
    __syncthreads();
    if (threadIdx.x == 0) {
        float s = 0.0f;
        const int nw = blockDim.x >> 6;
        for (int i = 0; i < nw; ++i) s += parts[i];
        atomicAdd(dst, s);
    }
}

__device__ __forceinline__ void async16(void* lds, const void* g) {
    __builtin_amdgcn_global_load_lds(
        (const __attribute__((address_space(1))) void*)g,
        (__attribute__((address_space(3))) void*)lds,
        16, 0, 0);
}

// ---------------- prep kernels ----------------

// W = mu + softplus(rho)*noise  (fp16), fused weight-KL
__global__ __launch_bounds__(256) void prep_w_kernel(
    const float4* __restrict__ mu4, const float4* __restrict__ rho4,
    const float4* __restrict__ nz4, f16x4* __restrict__ W4,
    float* __restrict__ kl_accum, int n4)
{
    float kl = 0.0f;
    const int stride = gridDim.x * blockDim.x;
    for (int i = blockIdx.x * blockDim.x + threadIdx.x; i < n4; i += stride) {
        const float4 m = mu4[i], r = rho4[i], z = nz4[i];
        const float mm[4] = {m.x, m.y, m.z, m.w};
        const float rr[4] = {r.x, r.y, r.z, r.w};
        const float zz[4] = {z.x, z.y, z.z, z.w};
        f16x4 w;
        #pragma unroll
        for (int c = 0; c < 4; ++c) {
            const float s = softplus_f(rr[c]);
            w[c] = (f16)(mm[c] + s * zz[c]);
            kl += 2.0f * __logf(s) + 1.0f / (s * s) + mm[c] * mm[c] - 1.0f;
        }
        W4[i] = w;
    }
    block_reduce_atomic(0.5f * kl, kl_accum);
}

// ard_scale, sampled bias, bias-KL + ard-KL. grid = 16 x 256 = 4096 threads.
__global__ __launch_bounds__(256) void prep_small_kernel(
    const float* __restrict__ bias_mu, const float* __restrict__ bias_rho,
    const float* __restrict__ alpha,   const float* __restrict__ beta,
    const float* __restrict__ bias_nz,
    float* __restrict__ ascale, float* __restrict__ bias,
    float* __restrict__ kl_accum)
{
    const int i = blockIdx.x * blockDim.x + threadIdx.x;
    float kl = 0.0f;
    if (i < IN_F) {
        const float sa = softplus_f(alpha[i]);
        const float sb = softplus_f(beta[i]);
        ascale[i] = sa * sb;
        kl += sa + sb - __logf(sa) - __logf(sb);
    }
    if (i < OUT_F) {
        const float s = softplus_f(bias_rho[i]);
        const float bm = bias_mu[i];
        bias[i] = bm + s * bias_nz[i];
        kl += 0.5f * (2.0f * __logf(s) + 1.0f / (s * s) + bm * bm - 1.0f);
    }
    block_reduce_atomic(kl, kl_accum);
}

// Xd = x * dropout_mask(u) * ard_scale[col]  (fp16)
__global__ __launch_bounds__(256) void prep_x_kernel(
    const float4* __restrict__ x4, const float4* __restrict__ u4,
    const float4* __restrict__ as4, f16x4* __restrict__ xd4, int n4)
{
    constexpr int C4 = IN_F / 4; // 1024
    const int stride = gridDim.x * blockDim.x;
    for (int i = blockIdx.x * blockDim.x + threadIdx.x; i < n4; i += stride) {
        const float4 xv = x4[i];
        const float4 uv = u4[i];
        const float4 av = as4[i & (C4 - 1)];
        f16x4 o;
        const float inv_keep = 1.0f / 0.9f;
        o[0] = (f16)((uv.x < 0.9f) ? xv.x * inv_keep * av.x : 0.0f);
        o[1] = (f16)((uv.y < 0.9f) ? xv.y * inv_keep * av.y : 0.0f);
        o[2] = (f16)((uv.z < 0.9f) ? xv.z * inv_keep * av.z : 0.0f);
        o[3] = (f16)((uv.w < 0.9f) ? xv.w * inv_keep * av.w : 0.0f);
        xd4[i] = o;
    }
}

// ---------------- GEMM: C[M][N] = A[M][K] * B[N][K]^T + bias ----------------
// m97-structure: 128x128 tile, BK=32, 4 waves (2x2), global_load_lds width 16,
// mfma_f32_16x16x32_f16, acc 4x4 fragments per wave.
__global__ __launch_bounds__(256, 2) void gemm_kernel(
    const f16* __restrict__ A, const f16* __restrict__ B,
    const float* __restrict__ bias, float* __restrict__ C)
{
    constexpr int M = BATCH, N = OUT_F, K = IN_F;
    constexpr int BM = 128, BN = 128, BK = 32;

    __shared__ f16 As[BM * BK]; // 8 KB
    __shared__ f16 Bs[BN * BK]; // 8 KB

    const int tid  = threadIdx.x;
    const int lane = tid & 63;
    const int wave = tid >> 6;
    const int nbn  = N / BN; // 32
    const int bm = blockIdx.x / nbn;
    const int bn = blockIdx.x % nbn;
    const int row0 = bm * BM, col0 = bn * BN;
    const int wr = wave >> 1, wc = wave & 1;
    const int fr = lane & 15, fq = lane >> 4;

    f32x4 acc[4][4] = {};

    // staging geometry: 8 chunks of 1024B per tile; wave w stages chunks w, w+4
    const int c0 = wave, c1 = wave + 4;
    const int srow = lane >> 2;        // 0..15 within chunk
    const int skk  = (lane & 3) << 3;  // 0,8,16,24 (halfs)

    const f16* Abase = A + (size_t)row0 * K;
    const f16* Bbase = B + (size_t)col0 * K;

    for (int k0 = 0; k0 < K; k0 += BK) {
        async16(&As[c0 * 512], Abase + (size_t)(c0 * 16 + srow) * K + k0 + skk);
        async16(&As[c1 * 512], Abase + (size_t)(c1 * 16 + srow) * K + k0 + skk);
        async16(&Bs[c0 * 512], Bbase + (size_t)(c0 * 16 + srow) * K + k0 + skk);
        async16(&Bs[c1 * 512], Bbase + (size_t)(c1 * 16 + srow) * K + k0 + skk);
        __syncthreads();

        f16x8 af[4], bf[4];
        #pragma unroll
        for (int m = 0; m < 4; ++m)
            af[m] = *(const f16x8*)&As[(wr * 64 + m * 16 + fr) * BK + fq * 8];
        #pragma unroll
        for (int n = 0; n < 4; ++n)
            bf[n] = *(const f16x8*)&Bs[(wc * 64 + n * 16 + fr) * BK + fq * 8];

        #pragma unroll
        for (int m = 0; m < 4; ++m)
            #pragma unroll
            for (int n = 0; n < 4; ++n)
                acc[m][n] = __builtin_amdgcn_mfma_f32_16x16x32_f16(
                    af[m], bf[n], acc[m][n], 0, 0, 0);
        __syncthreads();
    }

    // epilogue: D col = lane&15, row = (lane>>4)*4 + reg  [verified mapping]
    #pragma unroll
    for (int n = 0; n < 4; ++n) {
        const int ccol = col0 + wc * 64 + n * 16 + fr;
        const float bv = bias[ccol];
        #pragma unroll
        for (int m = 0; m < 4; ++m) {
            const int crow = row0 + wr * 64 + m * 16 + fq * 4;
            #pragma unroll
            for (int r = 0; r < 4; ++r)
                C[(size_t)(crow + r) * N + ccol] = acc[m][n][r] + bv;
        }
    }
}

__global__ void finalize_kernel(const float* __restrict__ kl, float* __restrict__ dst) {
    *dst = *kl;
}

// ---------------- launch ----------------

extern "C" void kernel_launch(void* const* d_in, const int* in_sizes, int n_in,
                              void* d_out, int out_size, void* d_ws, size_t ws_size,
                              hipStream_t stream)
{
    const float* x      = (const float*)d_in[0];
    const float* wmu    = (const float*)d_in[1];
    const float* wrho   = (const float*)d_in[2];
    const float* bmu    = (const float*)d_in[3];
    const float* brho   = (const float*)d_in[4];
    const float* alpha  = (const float*)d_in[5];
    const float* beta   = (const float*)d_in[6];
    const float* wnz    = (const float*)d_in[7];
    const float* bnz    = (const float*)d_in[8];
    const float* du     = (const float*)d_in[9];

    char* ws = (char*)d_ws;
    f16*   W      = (f16*)(ws);                                   // 33,554,432 B
    f16*   XD     = (f16*)(ws + 33554432);                        // 67,108,864 B
    float* ascale = (float*)(ws + 100663296);                     // 16 KB
    float* biasv  = (float*)(ws + 100679680);                     // 16 KB
    float* klacc  = (float*)(ws + 100696064);                     // 4 B

    float* out = (float*)d_out;

    hipMemsetAsync(klacc, 0, sizeof(float), stream);

    prep_small_kernel<<<16, 256, 0, stream>>>(bmu, brho, alpha, beta, bnz,
                                              ascale, biasv, klacc);
    prep_w_kernel<<<2048, 256, 0, stream>>>(
        (const float4*)wmu, (const float4*)wrho, (const float4*)wnz,
        (f16x4*)W, klacc, OUT_F * IN_F / 4);
    prep_x_kernel<<<2048, 256, 0, stream>>>(
        (const float4*)x, (const float4*)du, (const float4*)ascale,
        (f16x4*)XD, BATCH * IN_F / 4);

    gemm_kernel<<<(BATCH / 128) * (OUT_F / 128), 256, 0, stream>>>(XD, W, biasv, out);

    finalize_kernel<<<1, 1, 0, stream>>>(klacc, out + (size_t)BATCH * OUT_F);
}

// Round 2
// 383.417 us; speedup vs baseline: 1.2215x; 1.2215x over previous
//
#include <hip/hip_runtime.h>
#include <stdint.h>
#include <stddef.h>

#define IN_F  4096
#define OUT_F 4096
#define BATCH 8192

typedef _Float16 f16;
typedef _Float16 f16x4 __attribute__((ext_vector_type(4)));
typedef _Float16 f16x8 __attribute__((ext_vector_type(8)));
typedef float    f32x4 __attribute__((ext_vector_type(4)));

#define BARRIER() do { asm volatile("" ::: "memory"); __builtin_amdgcn_s_barrier(); asm volatile("" ::: "memory"); } while (0)
#define VMWAIT(n) asm volatile("s_waitcnt vmcnt(" #n ")" ::: "memory")

// ---------------- helpers ----------------

__device__ __forceinline__ float softplus_f(float x) {
    return fmaxf(x, 0.0f) + log1pf(__expf(-fabsf(x)));
}

__device__ __forceinline__ void block_reduce_atomic(float v, float* dst) {
    #pragma unroll
    for (int off = 32; off > 0; off >>= 1) v += __shfl_down(v, off, 64);
    __shared__ float parts[16];
    const int lane = threadIdx.x & 63, wave = threadIdx.x >> 6;
    if (lane == 0) parts[wave] = v;
    __syncthreads();
    if (threadIdx.x == 0) {
        float s = 0.0f;
        const int nw = blockDim.x >> 6;
        for (int i = 0; i < nw; ++i) s += parts[i];
        atomicAdd(dst, s);
    }
}

__device__ __forceinline__ void async16(void* lds, const void* g) {
    __builtin_amdgcn_global_load_lds(
        (const __attribute__((address_space(1))) void*)g,
        (__attribute__((address_space(3))) void*)lds,
        16, 0, 0);
}

// ---------------- prep kernels (unchanged, verified) ----------------

__global__ __launch_bounds__(256) void prep_w_kernel(
    const float4* __restrict__ mu4, const float4* __restrict__ rho4,
    const float4* __restrict__ nz4, f16x4* __restrict__ W4,
    float* __restrict__ kl_accum, int n4)
{
    float kl = 0.0f;
    const int stride = gridDim.x * blockDim.x;
    for (int i = blockIdx.x * blockDim.x + threadIdx.x; i < n4; i += stride) {
        const float4 m = mu4[i], r = rho4[i], z = nz4[i];
        const float mm[4] = {m.x, m.y, m.z, m.w};
        const float rr[4] = {r.x, r.y, r.z, r.w};
        const float zz[4] = {z.x, z.y, z.z, z.w};
        f16x4 w;
        #pragma unroll
        for (int c = 0; c < 4; ++c) {
            const float s = softplus_f(rr[c]);
            w[c] = (f16)(mm[c] + s * zz[c]);
            kl += 2.0f * __logf(s) + 1.0f / (s * s) + mm[c] * mm[c] - 1.0f;
        }
        W4[i] = w;
    }
    block_reduce_atomic(0.5f * kl, kl_accum);
}

__global__ __launch_bounds__(256) void prep_small_kernel(
    const float* __restrict__ bias_mu, const float* __restrict__ bias_rho,
    const float* __restrict__ alpha,   const float* __restrict__ beta,
    const float* __restrict__ bias_nz,
    float* __restrict__ ascale, float* __restrict__ bias,
    float* __restrict__ kl_accum)
{
    const int i = blockIdx.x * blockDim.x + threadIdx.x;
    float kl = 0.0f;
    if (i < IN_F) {
        const float sa = softplus_f(alpha[i]);
        const float sb = softplus_f(beta[i]);
        ascale[i] = sa * sb;
        kl += sa + sb - __logf(sa) - __logf(sb);
    }
    if (i < OUT_F) {
        const float s = softplus_f(bias_rho[i]);
        const float bm = bias_mu[i];
        bias[i] = bm + s * bias_nz[i];
        kl += 0.5f * (2.0f * __logf(s) + 1.0f / (s * s) + bm * bm - 1.0f);
    }
    block_reduce_atomic(kl, kl_accum);
}

__global__ __launch_bounds__(256) void prep_x_kernel(
    const float4* __restrict__ x4, const float4* __restrict__ u4,
    const float4* __restrict__ as4, f16x4* __restrict__ xd4, int n4)
{
    constexpr int C4 = IN_F / 4;
    const int stride = gridDim.x * blockDim.x;
    for (int i = blockIdx.x * blockDim.x + threadIdx.x; i < n4; i += stride) {
        const float4 xv = x4[i];
        const float4 uv = u4[i];
        const float4 av = as4[i & (C4 - 1)];
        f16x4 o;
        const float inv_keep = 1.0f / 0.9f;
        o[0] = (f16)((uv.x < 0.9f) ? xv.x * inv_keep * av.x : 0.0f);
        o[1] = (f16)((uv.y < 0.9f) ? xv.y * inv_keep * av.y : 0.0f);
        o[2] = (f16)((uv.z < 0.9f) ? xv.z * inv_keep * av.z : 0.0f);
        o[3] = (f16)((uv.w < 0.9f) ? xv.w * inv_keep * av.w : 0.0f);
        xd4[i] = o;
    }
}

// ---------------- GEMM: 256x256 tile, BK=64, 8-phase counted-vmcnt ----------------
// C[M][N] = A[M][K] * B[N][K]^T + bias.  8 waves (2Mx4N), interleaved wave tiling:
// frag (m,n) covers C rows m*32+wr*16+fq*4+r, cols n*64+wc*16+fr  (m 0..7, n 0..3).
// A-half0 = rows 0..127 (frags m0-3 for all waves), B-half0 = cols 0..127 (n0-1).
// LDS: 2 buffers x (A 32K + B 32K) = 128 KiB. Staging runs 2 K-tiles ahead, one
// half-tile (2 x global_load_lds) per phase into the region consumed last phase.
// One s_waitcnt vmcnt(6) per K-tile (3 half-tiles in flight). XOR swizzle
// u_phys = u ^ (row&7) on 16B units: pre-swizzled global source, swizzled ds_read.

#define QMFMA(MH, NH, AF, BF) do { \
    _Pragma("unroll") for (int mm_ = 0; mm_ < 4; ++mm_) \
    _Pragma("unroll") for (int nn_ = 0; nn_ < 2; ++nn_) \
    _Pragma("unroll") for (int ks_ = 0; ks_ < 2; ++ks_) \
        acc[(MH)*4+mm_][(NH)*2+nn_] = __builtin_amdgcn_mfma_f32_16x16x32_f16( \
            AF[mm_][ks_], BF[nn_][ks_], acc[(MH)*4+mm_][(NH)*2+nn_], 0, 0, 0); \
} while (0)

__global__ __launch_bounds__(512, 2) void gemm_kernel(
    const f16* __restrict__ A, const f16* __restrict__ B,
    const float* __restrict__ bias, float* __restrict__ C)
{
    constexpr int K = IN_F, N = OUT_F;
    constexpr int BK = 64, NT = K / BK; // 64 K-tiles

    extern __shared__ f16x8 smem_raw[];
    char* const smem = (char*)smem_raw;
    char* const sA = smem;          // [2][256][64] f16, unit-swizzled
    char* const sB = smem + 65536;  // [2][256][64] f16

    const int tid  = threadIdx.x;
    const int lane = tid & 63, wave = tid >> 6;
    const int wr = wave >> 2, wc = wave & 3;   // 2 x 4 waves
    const int fr = lane & 15, fq = lane >> 4;

    // XCD-aware block swizzle (512 wgs, 512%8==0 -> bijective)
    int bid = blockIdx.x;
    const int nbn = N / 256; // 16
    bid = (bid & 7) * 64 + (bid >> 3);
    const int row0 = (bid / nbn) * 256, col0 = (bid % nbn) * 256;

    // staging source (pre-swizzled so linear gload_lds dest + swizzled read match)
    const int srow  = tid >> 3;
    const int sunit = (tid & 7) ^ (srow & 7);
    const f16* gA = A + (size_t)(row0 + srow) * K + sunit * 8;
    const f16* gB = B + (size_t)(col0 + srow) * K + sunit * 8;
    const int sdst = tid * 16;

#define STA(T, H, J) async16(sA + ((T) & 1) * 32768 + (H) * 16384 + (J) * 8192 + sdst, \
                             gA + (size_t)((H) * 128 + (J) * 64) * K + (T) * 64)
#define STB(T, H, J) async16(sB + ((T) & 1) * 32768 + (H) * 16384 + (J) * 8192 + sdst, \
                             gB + (size_t)((H) * 128 + (J) * 64) * K + (T) * 64)

    // ds_read bases: byte = row*128 + ((u ^ (row&7))<<4), u = fq + 4*ks
    const int swz0 = (fq ^ (fr & 7)) << 4;
    const int arow = (wr * 16 + fr) * 128;
    const int brow = (wc * 16 + fr) * 128;

    f32x4 acc[8][4] = {};
    f16x8 a_lo[4][2], a_hi[4][2], b_lo[2][2], b_hi[2][2];

    // prologue: tile0 fully (consumption order A0,B0,A1,B1) + tile1 A0,B0,A1
    STA(0,0,0); STA(0,0,1); STB(0,0,0); STB(0,0,1);
    STA(0,1,0); STA(0,1,1); STB(0,1,0); STB(0,1,1);
    STA(1,0,0); STA(1,0,1); STB(1,0,0); STB(1,0,1);
    STA(1,1,0); STA(1,1,1);
    VMWAIT(6);   // tile0 landed, 3 half-tiles of tile1 in flight
    BARRIER();

    for (int t = 0; t < NT; ++t) {
        const int ab = (t & 1) * 32768;
        const int a0 = ab + arow + swz0;
        const int b0 = ab + brow + swz0;

        // ---- P0: read A-half0 | stage B1(t+1) | mfma q11 of tile t-1
        #pragma unroll
        for (int mm = 0; mm < 4; ++mm)
            #pragma unroll
            for (int ks = 0; ks < 2; ++ks)
                a_lo[mm][ks] = *(const f16x8*)(sA + ((a0 ^ (ks << 6)) + mm * 4096));
        if (t + 1 < NT) { STB(t+1, 1, 0); STB(t+1, 1, 1); }
        BARRIER();
        if (t > 0) {
            __builtin_amdgcn_s_setprio(1);
            QMFMA(1, 1, a_hi, b_hi);
            __builtin_amdgcn_s_setprio(0);
        }
        BARRIER();

        // ---- P1: read B-half0 | stage A0(t+2) | mfma q00
        #pragma unroll
        for (int nn = 0; nn < 2; ++nn)
            #pragma unroll
            for (int ks = 0; ks < 2; ++ks)
                b_lo[nn][ks] = *(const f16x8*)(sB + ((b0 ^ (ks << 6)) + nn * 8192));
        if (t + 2 < NT) { STA(t+2, 0, 0); STA(t+2, 0, 1); }
        BARRIER();
        __builtin_amdgcn_s_setprio(1);
        QMFMA(0, 0, a_lo, b_lo);
        __builtin_amdgcn_s_setprio(0);
        BARRIER();

        // ---- P2: read A-half1 | stage B0(t+2) | mfma q10
        #pragma unroll
        for (int mm = 0; mm < 4; ++mm)
            #pragma unroll
            for (int ks = 0; ks < 2; ++ks)
                a_hi[mm][ks] = *(const f16x8*)(sA + ((a0 ^ (ks << 6)) + 16384 + mm * 4096));
        if (t + 2 < NT) { STB(t+2, 0, 0); STB(t+2, 0, 1); }
        BARRIER();
        __builtin_amdgcn_s_setprio(1);
        QMFMA(1, 0, a_hi, b_lo);
        __builtin_amdgcn_s_setprio(0);
        BARRIER();

        // ---- P3: read B-half1 | stage A1(t+2) | mfma q01 | boundary vmcnt
        #pragma unroll
        for (int nn = 0; nn < 2; ++nn)
            #pragma unroll
            for (int ks = 0; ks < 2; ++ks)
                b_hi[nn][ks] = *(const f16x8*)(sB + ((b0 ^ (ks << 6)) + 16384 + nn * 8192));
        if (t + 2 < NT) { STA(t+2, 1, 0); STA(t+2, 1, 1); }
        BARRIER();
        __builtin_amdgcn_s_setprio(1);
        QMFMA(0, 1, a_lo, b_hi);
        __builtin_amdgcn_s_setprio(0);
        if (t < NT - 2) { VMWAIT(6); } else { VMWAIT(0); }
        BARRIER();
    }
    // final q11 of tile NT-1
    QMFMA(1, 1, a_hi, b_hi);

    // epilogue
    #pragma unroll
    for (int n = 0; n < 4; ++n) {
        const int col = col0 + n * 64 + wc * 16 + fr;
        const float bv = bias[col];
        #pragma unroll
        for (int m = 0; m < 8; ++m) {
            const int row = row0 + m * 32 + wr * 16 + fq * 4;
            #pragma unroll
            for (int r = 0; r < 4; ++r)
                C[(size_t)(row + r) * N + col] = acc[m][n][r] + bv;
        }
    }
#undef STA
#undef STB
}

__global__ void finalize_kernel(const float* __restrict__ kl, float* __restrict__ dst) {
    *dst = *kl;
}

// ---------------- launch ----------------

extern "C" void kernel_launch(void* const* d_in, const int* in_sizes, int n_in,
                              void* d_out, int out_size, void* d_ws, size_t ws_size,
                              hipStream_t stream)
{
    const float* x      = (const float*)d_in[0];
    const float* wmu    = (const float*)d_in[1];
    const float* wrho   = (const float*)d_in[2];
    const float* bmu    = (const float*)d_in[3];
    const float* brho   = (const float*)d_in[4];
    const float* alpha  = (const float*)d_in[5];
    const float* beta   = (const float*)d_in[6];
    const float* wnz    = (const float*)d_in[7];
    const float* bnz    = (const float*)d_in[8];
    const float* du     = (const float*)d_in[9];

    char* ws = (char*)d_ws;
    f16*   W      = (f16*)(ws);
    f16*   XD     = (f16*)(ws + 33554432);
    float* ascale = (float*)(ws + 100663296);
    float* biasv  = (float*)(ws + 100679680);
    float* klacc  = (float*)(ws + 100696064);

    float* out = (float*)d_out;

    hipMemsetAsync(klacc, 0, sizeof(float), stream);

    prep_small_kernel<<<16, 256, 0, stream>>>(bmu, brho, alpha, beta, bnz,
                                              ascale, biasv, klacc);
    prep_w_kernel<<<2048, 256, 0, stream>>>(
        (const float4*)wmu, (const float4*)wrho, (const float4*)wnz,
        (f16x4*)W, klacc, OUT_F * IN_F / 4);
    prep_x_kernel<<<2048, 256, 0, stream>>>(
        (const float4*)x, (const float4*)du, (const float4*)ascale,
        (f16x4*)XD, BATCH * IN_F / 4);

    hipFuncSetAttribute((const void*)gemm_kernel,
                        hipFuncAttributeMaxDynamicSharedMemorySize, 131072);
    gemm_kernel<<<512, 512, 131072, stream>>>(XD, W, biasv, out);

    finalize_kernel<<<1, 1, 0, stream>>>(klacc, out + (size_t)BATCH * OUT_F);
}

// Round 3
// 382.701 us; speedup vs baseline: 1.2238x; 1.0019x over previous
//
#include <hip/hip_runtime.h>
#include <stdint.h>
#include <stddef.h>

#define IN_F  4096
#define OUT_F 4096
#define BATCH 8192

typedef _Float16 f16;
typedef _Float16 f16x4 __attribute__((ext_vector_type(4)));
typedef _Float16 f16x8 __attribute__((ext_vector_type(8)));
typedef float    f32x4 __attribute__((ext_vector_type(4)));

#define BARRIER() do { asm volatile("" ::: "memory"); __builtin_amdgcn_s_barrier(); asm volatile("" ::: "memory"); } while (0)
#define VMWAIT(n) asm volatile("s_waitcnt vmcnt(" #n ")" ::: "memory")

// ---------------- helpers ----------------

__device__ __forceinline__ float softplus_f(float x) {
    return fmaxf(x, 0.0f) + log1pf(__expf(-fabsf(x)));
}

__device__ __forceinline__ void block_reduce_atomic(float v, float* dst) {
    #pragma unroll
    for (int off = 32; off > 0; off >>= 1) v += __shfl_down(v, off, 64);
    __shared__ float parts[16];
    const int lane = threadIdx.x & 63, wave = threadIdx.x >> 6;
    if (lane == 0) parts[wave] = v;
    __syncthreads();
    if (threadIdx.x == 0) {
        float s = 0.0f;
        const int nw = blockDim.x >> 6;
        for (int i = 0; i < nw; ++i) s += parts[i];
        atomicAdd(dst, s);
    }
}

__device__ __forceinline__ void async16(void* lds, const void* g) {
    __builtin_amdgcn_global_load_lds(
        (const __attribute__((address_space(1))) void*)g,
        (__attribute__((address_space(3))) void*)lds,
        16, 0, 0);
}

// ---------------- prep kernels (unchanged, verified) ----------------

__global__ __launch_bounds__(256) void prep_w_kernel(
    const float4* __restrict__ mu4, const float4* __restrict__ rho4,
    const float4* __restrict__ nz4, f16x4* __restrict__ W4,
    float* __restrict__ kl_accum, int n4)
{
    float kl = 0.0f;
    const int stride = gridDim.x * blockDim.x;
    for (int i = blockIdx.x * blockDim.x + threadIdx.x; i < n4; i += stride) {
        const float4 m = mu4[i], r = rho4[i], z = nz4[i];
        const float mm[4] = {m.x, m.y, m.z, m.w};
        const float rr[4] = {r.x, r.y, r.z, r.w};
        const float zz[4] = {z.x, z.y, z.z, z.w};
        f16x4 w;
        #pragma unroll
        for (int c = 0; c < 4; ++c) {
            const float s = softplus_f(rr[c]);
            w[c] = (f16)(mm[c] + s * zz[c]);
            kl += 2.0f * __logf(s) + 1.0f / (s * s) + mm[c] * mm[c] - 1.0f;
        }
        W4[i] = w;
    }
    block_reduce_atomic(0.5f * kl, kl_accum);
}

__global__ __launch_bounds__(256) void prep_small_kernel(
    const float* __restrict__ bias_mu, const float* __restrict__ bias_rho,
    const float* __restrict__ alpha,   const float* __restrict__ beta,
    const float* __restrict__ bias_nz,
    float* __restrict__ ascale, float* __restrict__ bias,
    float* __restrict__ kl_accum)
{
    const int i = blockIdx.x * blockDim.x + threadIdx.x;
    float kl = 0.0f;
    if (i < IN_F) {
        const float sa = softplus_f(alpha[i]);
        const float sb = softplus_f(beta[i]);
        ascale[i] = sa * sb;
        kl += sa + sb - __logf(sa) - __logf(sb);
    }
    if (i < OUT_F) {
        const float s = softplus_f(bias_rho[i]);
        const float bm = bias_mu[i];
        bias[i] = bm + s * bias_nz[i];
        kl += 0.5f * (2.0f * __logf(s) + 1.0f / (s * s) + bm * bm - 1.0f);
    }
    block_reduce_atomic(kl, kl_accum);
}

__global__ __launch_bounds__(256) void prep_x_kernel(
    const float4* __restrict__ x4, const float4* __restrict__ u4,
    const float4* __restrict__ as4, f16x4* __restrict__ xd4, int n4)
{
    constexpr int C4 = IN_F / 4;
    const int stride = gridDim.x * blockDim.x;
    for (int i = blockIdx.x * blockDim.x + threadIdx.x; i < n4; i += stride) {
        const float4 xv = x4[i];
        const float4 uv = u4[i];
        const float4 av = as4[i & (C4 - 1)];
        f16x4 o;
        const float inv_keep = 1.0f / 0.9f;
        o[0] = (f16)((uv.x < 0.9f) ? xv.x * inv_keep * av.x : 0.0f);
        o[1] = (f16)((uv.y < 0.9f) ? xv.y * inv_keep * av.y : 0.0f);
        o[2] = (f16)((uv.z < 0.9f) ? xv.z * inv_keep * av.z : 0.0f);
        o[3] = (f16)((uv.w < 0.9f) ? xv.w * inv_keep * av.w : 0.0f);
        xd4[i] = o;
    }
}

// ---------------- GEMM: 256x256 tile, BK=64, 8-phase counted-vmcnt ----------------
// C[M][N] = A[M][K] * B[N][K]^T + bias.  8 waves (2Mx4N), interleaved wave tiling.
// Deferred-quadrant schedule: every MFMA cluster consumes only registers read
// >=1 phase earlier (q10/q11 of tile t run at P0/P1 of tile t+1).
//   P0: read a_lo(t) | stage A1(t+1) | mfma q10(t-1)
//   P1: read b_lo(t) | stage A0(t+2) | mfma q11(t-1)
//   P2: read b_hi(t) | stage B0(t+2) | mfma q00(t)
//   P3: read a_hi(t) | stage B1(t+2) | mfma q01(t) | vmcnt(6) | barrier
// One vmcnt(6) per K-tile (3 half-tiles in flight). XOR swizzle u^(row&7) on
// 16B units: pre-swizzled global source (linear gload_lds dest), swizzled ds_read.

#define QMFMA(MH, NH, AF, BF) do { \
    _Pragma("unroll") for (int mm_ = 0; mm_ < 4; ++mm_) \
    _Pragma("unroll") for (int nn_ = 0; nn_ < 2; ++nn_) \
    _Pragma("unroll") for (int ks_ = 0; ks_ < 2; ++ks_) \
        acc[(MH)*4+mm_][(NH)*2+nn_] = __builtin_amdgcn_mfma_f32_16x16x32_f16( \
            AF[mm_][ks_], BF[nn_][ks_], acc[(MH)*4+mm_][(NH)*2+nn_], 0, 0, 0); \
} while (0)

__global__ __launch_bounds__(512, 2) void gemm_kernel(
    const f16* __restrict__ A, const f16* __restrict__ B,
    const float* __restrict__ bias, float* __restrict__ C)
{
    constexpr int K = IN_F, N = OUT_F;
    constexpr int BK = 64, NT = K / BK; // 64 K-tiles

    extern __shared__ f16x8 smem_raw[];
    char* const smem = (char*)smem_raw;
    char* const sA = smem;          // [2][256][64] f16, unit-swizzled
    char* const sB = smem + 65536;  // [2][256][64] f16

    const int tid  = threadIdx.x;
    const int lane = tid & 63, wave = tid >> 6;
    const int wr = wave >> 2, wc = wave & 3;   // 2 x 4 waves
    const int fr = lane & 15, fq = lane >> 4;

    // XCD-aware block swizzle (512 wgs, 512%8==0 -> bijective)
    int bid = blockIdx.x;
    const int nbn = N / 256; // 16
    bid = (bid & 7) * 64 + (bid >> 3);
    const int row0 = (bid / nbn) * 256, col0 = (bid % nbn) * 256;

    // staging source (pre-swizzled so linear gload_lds dest + swizzled read match)
    const int srow  = tid >> 3;
    const int sunit = (tid & 7) ^ (srow & 7);
    const f16* gA = A + (size_t)(row0 + srow) * K + sunit * 8;
    const f16* gB = B + (size_t)(col0 + srow) * K + sunit * 8;
    const int sdst = tid * 16;

#define STA(T, H, J) async16(sA + ((T) & 1) * 32768 + (H) * 16384 + (J) * 8192 + sdst, \
                             gA + (size_t)((H) * 128 + (J) * 64) * K + (T) * 64)
#define STB(T, H, J) async16(sB + ((T) & 1) * 32768 + (H) * 16384 + (J) * 8192 + sdst, \
                             gB + (size_t)((H) * 128 + (J) * 64) * K + (T) * 64)

    // ds_read bases: byte = row*128 + (((fq+4*ks) ^ (row&7))<<4)
    const int swz0 = (fq ^ (fr & 7)) << 4;
    const int arow = (wr * 16 + fr) * 128;
    const int brow = (wc * 16 + fr) * 128;

    f32x4 acc[8][4] = {};
    f16x8 a_lo[4][2], a_hi[4][2], b_lo[2][2], b_hi[2][2];

    // prologue: tile0 in consumption order (A0,B0,B1,A1) + tile1 A0,B0,B1
    STA(0,0,0); STA(0,0,1); STB(0,0,0); STB(0,0,1);
    STB(0,1,0); STB(0,1,1); STA(0,1,0); STA(0,1,1);
    STA(1,0,0); STA(1,0,1); STB(1,0,0); STB(1,0,1);
    STB(1,1,0); STB(1,1,1);
    VMWAIT(6);   // tile0 landed; tile1 A0,B0,B1 in flight
    BARRIER();

    for (int t = 0; t < NT; ++t) {
        const int ab = (t & 1) * 32768;
        const int a0 = ab + arow + swz0;
        const int b0 = ab + brow + swz0;

        // ---- P0: read a_lo(t) | stage A1(t+1) | mfma q10(t-1)
        #pragma unroll
        for (int mm = 0; mm < 4; ++mm)
            #pragma unroll
            for (int ks = 0; ks < 2; ++ks)
                a_lo[mm][ks] = *(const f16x8*)(sA + ((a0 ^ (ks << 6)) + mm * 4096));
        if (t + 1 < NT) { STA(t+1, 1, 0); STA(t+1, 1, 1); }
        BARRIER();
        if (t > 0) {
            __builtin_amdgcn_s_setprio(1);
            QMFMA(1, 0, a_hi, b_lo);
            __builtin_amdgcn_s_setprio(0);
        }
        BARRIER();

        // ---- P1: read b_lo(t) | stage A0(t+2) | mfma q11(t-1)
        #pragma unroll
        for (int nn = 0; nn < 2; ++nn)
            #pragma unroll
            for (int ks = 0; ks < 2; ++ks)
                b_lo[nn][ks] = *(const f16x8*)(sB + ((b0 ^ (ks << 6)) + nn * 8192));
        if (t + 2 < NT) { STA(t+2, 0, 0); STA(t+2, 0, 1); }
        BARRIER();
        if (t > 0) {
            __builtin_amdgcn_s_setprio(1);
            QMFMA(1, 1, a_hi, b_hi);
            __builtin_amdgcn_s_setprio(0);
        }
        BARRIER();

        // ---- P2: read b_hi(t) | stage B0(t+2) | mfma q00(t)
        #pragma unroll
        for (int nn = 0; nn < 2; ++nn)
            #pragma unroll
            for (int ks = 0; ks < 2; ++ks)
                b_hi[nn][ks] = *(const f16x8*)(sB + ((b0 ^ (ks << 6)) + 16384 + nn * 8192));
        if (t + 2 < NT) { STB(t+2, 0, 0); STB(t+2, 0, 1); }
        BARRIER();
        __builtin_amdgcn_s_setprio(1);
        QMFMA(0, 0, a_lo, b_lo);
        __builtin_amdgcn_s_setprio(0);
        BARRIER();

        // ---- P3: read a_hi(t) | stage B1(t+2) | mfma q01(t) | boundary vmcnt
        #pragma unroll
        for (int mm = 0; mm < 4; ++mm)
            #pragma unroll
            for (int ks = 0; ks < 2; ++ks)
                a_hi[mm][ks] = *(const f16x8*)(sA + ((a0 ^ (ks << 6)) + 16384 + mm * 4096));
        if (t + 2 < NT) { STB(t+2, 1, 0); STB(t+2, 1, 1); }
        BARRIER();
        __builtin_amdgcn_s_setprio(1);
        QMFMA(0, 1, a_lo, b_hi);
        __builtin_amdgcn_s_setprio(0);
        if (t < NT - 2) { VMWAIT(6); } else { VMWAIT(0); }
        BARRIER();
    }
    // deferred quadrants of tile NT-1
    QMFMA(1, 0, a_hi, b_lo);
    QMFMA(1, 1, a_hi, b_hi);

    // epilogue
    #pragma unroll
    for (int n = 0; n < 4; ++n) {
        const int col = col0 + n * 64 + wc * 16 + fr;
        const float bv = bias[col];
        #pragma unroll
        for (int m = 0; m < 8; ++m) {
            const int row = row0 + m * 32 + wr * 16 + fq * 4;
            #pragma unroll
            for (int r = 0; r < 4; ++r)
                C[(size_t)(row + r) * N + col] = acc[m][n][r] + bv;
        }
    }
#undef STA
#undef STB
}

__global__ void finalize_kernel(const float* __restrict__ kl, float* __restrict__ dst) {
    *dst = *kl;
}

// ---------------- launch ----------------

extern "C" void kernel_launch(void* const* d_in, const int* in_sizes, int n_in,
                              void* d_out, int out_size, void* d_ws, size_t ws_size,
                              hipStream_t stream)
{
    const float* x      = (const float*)d_in[0];
    const float* wmu    = (const float*)d_in[1];
    const float* wrho   = (const float*)d_in[2];
    const float* bmu    = (const float*)d_in[3];
    const float* brho   = (const float*)d_in[4];
    const float* alpha  = (const float*)d_in[5];
    const float* beta   = (const float*)d_in[6];
    const float* wnz    = (const float*)d_in[7];
    const float* bnz    = (const float*)d_in[8];
    const float* du     = (const float*)d_in[9];

    char* ws = (char*)d_ws;
    f16*   W      = (f16*)(ws);
    f16*   XD     = (f16*)(ws + 33554432);
    float* ascale = (float*)(ws + 100663296);
    float* biasv  = (float*)(ws + 100679680);
    float* klacc  = (float*)(ws + 100696064);

    float* out = (float*)d_out;

    hipMemsetAsync(klacc, 0, sizeof(float), stream);

    prep_small_kernel<<<16, 256, 0, stream>>>(bmu, brho, alpha, beta, bnz,
                                              ascale, biasv, klacc);
    prep_w_kernel<<<2048, 256, 0, stream>>>(
        (const float4*)wmu, (const float4*)wrho, (const float4*)wnz,
        (f16x4*)W, klacc, OUT_F * IN_F / 4);
    prep_x_kernel<<<2048, 256, 0, stream>>>(
        (const float4*)x, (const float4*)du, (const float4*)ascale,
        (f16x4*)XD, BATCH * IN_F / 4);

    hipFuncSetAttribute((const void*)gemm_kernel,
                        hipFuncAttributeMaxDynamicSharedMemorySize, 131072);
    gemm_kernel<<<512, 512, 131072, stream>>>(XD, W, biasv, out);

    finalize_kernel<<<1, 1, 0, stream>>>(klacc, out + (size_t)BATCH * OUT_F);
}